// Round 1
// baseline (73.741 us; speedup 1.0000x reference)
//
#include <hip/hip_runtime.h>
#include <math.h>

#define BB 32
#define CC 256
#define HH 64
#define WW 64
#define RR 16
#define HWSZ (HH * WW)          // 4096
#define POS 205                 // max(1, round(0.8 * 256))

// ---------------------------------------------------------------------------
// Kernel 1: per-(b,c) mean over H*W = 4096 elements.
// One 256-thread block per row; each thread sums 4 float4 (16 floats).
// ---------------------------------------------------------------------------
__global__ void mean_kernel(const float* __restrict__ x, float* __restrict__ y) {
    const int row = blockIdx.x;                      // 0 .. B*C-1
    const float4* xr = (const float4*)(x + (size_t)row * HWSZ);
    const int t = threadIdx.x;                       // 0 .. 255
    float s = 0.f;
#pragma unroll
    for (int i = 0; i < 4; ++i) {
        float4 v = xr[t + i * 256];
        s += v.x + v.y + v.z + v.w;
    }
    // wave (64-lane) reduce
#pragma unroll
    for (int off = 32; off > 0; off >>= 1) s += __shfl_down(s, off, 64);
    __shared__ float red[4];                         // 4 waves / block
    const int wave = t >> 6;
    if ((t & 63) == 0) red[wave] = s;
    __syncthreads();
    if (t == 0) {
        float tot = red[0] + red[1] + red[2] + red[3];
        y[row] = tot * (1.0f / (float)HWSZ);
    }
}

// ---------------------------------------------------------------------------
// Kernel 2: SE bottleneck + rank-based threshold mask. One block per batch b.
//   h[r] = relu(sum_c y[c] * W1[r,c])
//   s[c] = sigmoid(sum_r h[r] * W2[c,r])
//   mask[c] = (#{j : s[j] < s[c]} <= POS-1)   ==   (s[c] <= sorted(s)[POS-1])
// ---------------------------------------------------------------------------
__global__ void se_kernel(const float* __restrict__ y,
                          const float* __restrict__ W1,
                          const float* __restrict__ W2,
                          float* __restrict__ mask) {
    const int b = blockIdx.x;
    const int c = threadIdx.x;                       // 0 .. 255
    __shared__ float ys[CC];
    __shared__ float hs[RR];
    __shared__ float ss[CC];

    ys[c] = y[b * CC + c];
    __syncthreads();

    if (c < RR) {
        float acc = 0.f;
        for (int j = 0; j < CC; ++j) acc += ys[j] * W1[c * CC + j];
        hs[c] = fmaxf(acc, 0.f);
    }
    __syncthreads();

    float acc = 0.f;
#pragma unroll
    for (int r = 0; r < RR; ++r) acc += hs[r] * W2[c * RR + r];
    const float s = 1.0f / (1.0f + expf(-acc));
    ss[c] = s;
    __syncthreads();

    int cnt = 0;
    for (int j = 0; j < CC; ++j) cnt += (ss[j] < s) ? 1 : 0;
    mask[b * CC + c] = (cnt <= POS - 1) ? 1.0f : 0.0f;
}

// ---------------------------------------------------------------------------
// Kernel 3: out = x * mask[b,c], float4 grid-stride.
// 1024 float4 per (b,c) row -> mask index = i >> 10.
// ---------------------------------------------------------------------------
__global__ void apply_kernel(const float* __restrict__ x,
                             const float* __restrict__ mask,
                             float* __restrict__ out) {
    const size_t n4 = (size_t)BB * CC * HWSZ / 4;
    size_t i = (size_t)blockIdx.x * blockDim.x + threadIdx.x;
    const size_t stride = (size_t)gridDim.x * blockDim.x;
    const float4* x4 = (const float4*)x;
    float4* o4 = (float4*)out;
    for (; i < n4; i += stride) {
        const float m = mask[i >> 10];
        float4 v = x4[i];
        v.x *= m; v.y *= m; v.z *= m; v.w *= m;
        o4[i] = v;
    }
}

extern "C" void kernel_launch(void* const* d_in, const int* in_sizes, int n_in,
                              void* d_out, int out_size, void* d_ws, size_t ws_size,
                              hipStream_t stream) {
    const float* x  = (const float*)d_in[0];
    const float* W1 = (const float*)d_in[1];
    const float* W2 = (const float*)d_in[2];
    float* out = (float*)d_out;

    float* y    = (float*)d_ws;                 // B*C floats
    float* mask = y + BB * CC;                  // B*C floats

    mean_kernel<<<BB * CC, 256, 0, stream>>>(x, y);
    se_kernel<<<BB, 256, 0, stream>>>(y, W1, W2, mask);
    apply_kernel<<<2048, 256, 0, stream>>>(x, mask, out);
}

// Round 3
// 71.493 us; speedup vs baseline: 1.0314x; 1.0314x over previous
//
#include <hip/hip_runtime.h>
#include <math.h>

#define BB 32
#define CC 256
#define HH 64
#define WW 64
#define RR 16
#define HWSZ (HH * WW)          // 4096
#define POS 205                 // max(1, round(0.8 * 256))

typedef float f32x4 __attribute__((ext_vector_type(4)));

// ---------------------------------------------------------------------------
// Kernel 1: per-(b,c) mean over H*W = 4096 elements.
// One 256-thread block per row; each thread sums 4 float4 (16 floats).
// Regular (caching) loads on purpose: this pass warms L2/L3 with x so the
// apply pass can re-read it from cache.
// ---------------------------------------------------------------------------
__global__ void mean_kernel(const float* __restrict__ x, float* __restrict__ y) {
    const int row = blockIdx.x;                      // 0 .. B*C-1
    const f32x4* xr = (const f32x4*)(x + (size_t)row * HWSZ);
    const int t = threadIdx.x;                       // 0 .. 255
    float s = 0.f;
#pragma unroll
    for (int i = 0; i < 4; ++i) {
        f32x4 v = xr[t + i * 256];
        s += v.x + v.y + v.z + v.w;
    }
    // wave (64-lane) reduce
#pragma unroll
    for (int off = 32; off > 0; off >>= 1) s += __shfl_down(s, off, 64);
    __shared__ float red[4];                         // 4 waves / block
    const int wave = t >> 6;
    if ((t & 63) == 0) red[wave] = s;
    __syncthreads();
    if (t == 0) {
        float tot = red[0] + red[1] + red[2] + red[3];
        y[row] = tot * (1.0f / (float)HWSZ);
    }
}

// ---------------------------------------------------------------------------
// Kernel 2: SE bottleneck + rank-based threshold mask. One block per batch b.
//   h[r] = relu(sum_c y[c] * W1[r,c])
//   s[c] = sigmoid(sum_r h[r] * W2[c,r])
//   mask[c] = (#{j : s[j] < s[c]} <= POS-1)   ==   (s[c] <= sorted(s)[POS-1])
// ---------------------------------------------------------------------------
__global__ void se_kernel(const float* __restrict__ y,
                          const float* __restrict__ W1,
                          const float* __restrict__ W2,
                          float* __restrict__ mask) {
    const int b = blockIdx.x;
    const int c = threadIdx.x;                       // 0 .. 255
    __shared__ float ys[CC];
    __shared__ float hs[RR];
    __shared__ float ss[CC];

    ys[c] = y[b * CC + c];
    __syncthreads();

    if (c < RR) {
        float acc = 0.f;
        for (int j = 0; j < CC; ++j) acc += ys[j] * W1[c * CC + j];
        hs[c] = fmaxf(acc, 0.f);
    }
    __syncthreads();

    float acc = 0.f;
#pragma unroll
    for (int r = 0; r < RR; ++r) acc += hs[r] * W2[c * RR + r];
    const float s = 1.0f / (1.0f + expf(-acc));
    ss[c] = s;
    __syncthreads();

    int cnt = 0;
    for (int j = 0; j < CC; ++j) cnt += (ss[j] < s) ? 1 : 0;
    mask[b * CC + c] = (cnt <= POS - 1) ? 1.0f : 0.0f;
}

// ---------------------------------------------------------------------------
// Kernel 3: out = x * mask[b,c], float4 grid-stride.
// 1024 float4 per (b,c) row -> mask index = i >> 10.
// Non-temporal stores: out is write-once, never read — keep it from evicting
// x (which we want to re-read from LLC, not HBM).
// ---------------------------------------------------------------------------
__global__ void apply_kernel(const float* __restrict__ x,
                             const float* __restrict__ mask,
                             float* __restrict__ out) {
    const size_t n4 = (size_t)BB * CC * HWSZ / 4;
    size_t i = (size_t)blockIdx.x * blockDim.x + threadIdx.x;
    const size_t stride = (size_t)gridDim.x * blockDim.x;
    const f32x4* x4 = (const f32x4*)x;
    f32x4* o4 = (f32x4*)out;
    for (; i < n4; i += stride) {
        const float m = mask[i >> 10];
        f32x4 v = x4[i];
        v *= m;
        __builtin_nontemporal_store(v, &o4[i]);
    }
}

extern "C" void kernel_launch(void* const* d_in, const int* in_sizes, int n_in,
                              void* d_out, int out_size, void* d_ws, size_t ws_size,
                              hipStream_t stream) {
    const float* x  = (const float*)d_in[0];
    const float* W1 = (const float*)d_in[1];
    const float* W2 = (const float*)d_in[2];
    float* out = (float*)d_out;

    float* y    = (float*)d_ws;                 // B*C floats
    float* mask = y + BB * CC;                  // B*C floats

    mean_kernel<<<BB * CC, 256, 0, stream>>>(x, y);
    se_kernel<<<BB, 256, 0, stream>>>(y, W1, W2, mask);
    apply_kernel<<<4096, 256, 0, stream>>>(x, mask, out);
}

// Round 4
// 63.901 us; speedup vs baseline: 1.1540x; 1.1188x over previous
//
#include <hip/hip_runtime.h>
#include <math.h>

#define BB 32
#define CC 256
#define HH 64
#define WW 64
#define RR 16
#define HWSZ (HH * WW)          // 4096
#define POS 205                 // max(1, round(0.8 * 256))

typedef float f32x4 __attribute__((ext_vector_type(4)));

// ---------------------------------------------------------------------------
// Kernel 1: per-(b,c) mean over H*W = 4096 elements.
// One 256-thread block per row; each thread sums 4 float4 (16 floats).
// Regular (caching) loads: warms LLC with x for the apply pass re-read.
// ---------------------------------------------------------------------------
__global__ void mean_kernel(const float* __restrict__ x, float* __restrict__ y) {
    const int row = blockIdx.x;                      // 0 .. B*C-1
    const f32x4* xr = (const f32x4*)(x + (size_t)row * HWSZ);
    const int t = threadIdx.x;                       // 0 .. 255
    float s = 0.f;
#pragma unroll
    for (int i = 0; i < 4; ++i) {
        f32x4 v = xr[t + i * 256];
        s += v.x + v.y + v.z + v.w;
    }
#pragma unroll
    for (int off = 32; off > 0; off >>= 1) s += __shfl_down(s, off, 64);
    __shared__ float red[4];
    const int wave = t >> 6;
    if ((t & 63) == 0) red[wave] = s;
    __syncthreads();
    if (t == 0) {
        float tot = red[0] + red[1] + red[2] + red[3];
        y[row] = tot * (1.0f / (float)HWSZ);
    }
}

// ---------------------------------------------------------------------------
// Kernel 2: SE bottleneck + rank-based threshold mask. One block per batch b.
//   h[r] = relu(sum_c y[c] * W1[r,c])   -- parallel: 16 lanes x 16 elems per r
//   s[c] = sigmoid(sum_r h[r] * W2[c,r])
//   mask[c] = (#{j : s[j] < s[c]} <= POS-1)  ==  (s[c] <= sorted(s)[POS-1])
// ---------------------------------------------------------------------------
__global__ void se_kernel(const float* __restrict__ y,
                          const float* __restrict__ W1,
                          const float* __restrict__ W2,
                          float* __restrict__ mask) {
    const int b = blockIdx.x;
    const int t = threadIdx.x;                       // 0 .. 255
    __shared__ float ys[CC];
    __shared__ float hs[RR];
    __shared__ float ss[CC];

    ys[t] = y[b * CC + t];
    __syncthreads();

    {   // h[r]: r = t>>4 (0..15), each group of 16 lanes splits the 256-dot
        const int r = t >> 4;
        const int p = t & 15;
        float acc = 0.f;
#pragma unroll
        for (int j = 0; j < 16; ++j)
            acc += ys[p * 16 + j] * W1[r * CC + p * 16 + j];
        // reduce across the 16-lane group (consecutive lanes, same wave)
#pragma unroll
        for (int off = 8; off > 0; off >>= 1) acc += __shfl_xor(acc, off, 16);
        if (p == 0) hs[r] = fmaxf(acc, 0.f);
    }
    __syncthreads();

    float acc = 0.f;
#pragma unroll
    for (int r = 0; r < RR; ++r) acc += hs[r] * W2[t * RR + r];
    const float s = 1.0f / (1.0f + expf(-acc));
    ss[t] = s;
    __syncthreads();

    int cnt = 0;
    for (int j = 0; j < CC; ++j) cnt += (ss[j] < s) ? 1 : 0;
    mask[b * CC + t] = (cnt <= POS - 1) ? 1.0f : 0.0f;
}

// ---------------------------------------------------------------------------
// Kernel 3: one block per (b,c) row. Block-uniform mask: masked-off rows
// store zeros WITHOUT reading x (saves ~20% of the second x read).
// NT stores keep the write stream from evicting x in LLC.
// ---------------------------------------------------------------------------
__global__ void apply_kernel(const float* __restrict__ x,
                             const float* __restrict__ mask,
                             float* __restrict__ out) {
    const int row = blockIdx.x;                      // 0 .. B*C-1
    const int t = threadIdx.x;                       // 0 .. 255
    const float m = mask[row];                       // block-uniform
    f32x4* orow = (f32x4*)(out + (size_t)row * HWSZ);
    if (m == 0.0f) {
        f32x4 z = {0.f, 0.f, 0.f, 0.f};
#pragma unroll
        for (int i = 0; i < 4; ++i)
            __builtin_nontemporal_store(z, &orow[t + i * 256]);
    } else {
        const f32x4* xr = (const f32x4*)(x + (size_t)row * HWSZ);
#pragma unroll
        for (int i = 0; i < 4; ++i) {
            f32x4 v = xr[t + i * 256];
            __builtin_nontemporal_store(v, &orow[t + i * 256]);
        }
    }
}

extern "C" void kernel_launch(void* const* d_in, const int* in_sizes, int n_in,
                              void* d_out, int out_size, void* d_ws, size_t ws_size,
                              hipStream_t stream) {
    const float* x  = (const float*)d_in[0];
    const float* W1 = (const float*)d_in[1];
    const float* W2 = (const float*)d_in[2];
    float* out = (float*)d_out;

    float* y    = (float*)d_ws;                 // B*C floats
    float* mask = y + BB * CC;                  // B*C floats

    mean_kernel<<<BB * CC, 256, 0, stream>>>(x, y);
    se_kernel<<<BB, 256, 0, stream>>>(y, W1, W2, mask);
    apply_kernel<<<BB * CC, 256, 0, stream>>>(x, mask, out);
}

// Round 5
// 58.252 us; speedup vs baseline: 1.2659x; 1.0970x over previous
//
#include <hip/hip_runtime.h>
#include <math.h>

#define BB 32
#define CC 256
#define HH 64
#define WW 64
#define RR 16
#define HWSZ (HH * WW)          // 4096
#define POS 205                 // max(1, round(0.8 * 256))

typedef float f32x4 __attribute__((ext_vector_type(4)));

// ---------------------------------------------------------------------------
// Kernel 1: fused copy + mean. One block per (b,c) row.
// Streams x exactly once: NT-load 16 KiB, NT-store to out, accumulate mean.
// Masked-off rows get overwritten with zeros by kernel 3 afterwards.
// ---------------------------------------------------------------------------
__global__ void mean_copy_kernel(const float* __restrict__ x,
                                 float* __restrict__ out,
                                 float* __restrict__ y) {
    const int row = blockIdx.x;                      // 0 .. B*C-1
    const f32x4* xr = (const f32x4*)(x + (size_t)row * HWSZ);
    f32x4* orow = (f32x4*)(out + (size_t)row * HWSZ);
    const int t = threadIdx.x;                       // 0 .. 255
    float s = 0.f;
#pragma unroll
    for (int i = 0; i < 4; ++i) {
        f32x4 v = __builtin_nontemporal_load(&xr[t + i * 256]);
        __builtin_nontemporal_store(v, &orow[t + i * 256]);
        s += v.x + v.y + v.z + v.w;
    }
#pragma unroll
    for (int off = 32; off > 0; off >>= 1) s += __shfl_down(s, off, 64);
    __shared__ float red[4];
    const int wave = t >> 6;
    if ((t & 63) == 0) red[wave] = s;
    __syncthreads();
    if (t == 0) {
        float tot = red[0] + red[1] + red[2] + red[3];
        y[row] = tot * (1.0f / (float)HWSZ);
    }
}

// ---------------------------------------------------------------------------
// Kernel 2: SE bottleneck + rank-based threshold mask. One block per batch b.
//   h[r] = relu(sum_c y[c] * W1[r,c])   -- 16 lanes x 16 elems per r
//   s[c] = sigmoid(sum_r h[r] * W2[c,r])
//   mask[c] = (#{j : s[j] < s[c]} <= POS-1)  ==  (s[c] <= sorted(s)[POS-1])
// ---------------------------------------------------------------------------
__global__ void se_kernel(const float* __restrict__ y,
                          const float* __restrict__ W1,
                          const float* __restrict__ W2,
                          float* __restrict__ mask) {
    const int b = blockIdx.x;
    const int t = threadIdx.x;                       // 0 .. 255
    __shared__ float ys[CC];
    __shared__ float hs[RR];
    __shared__ float ss[CC];

    ys[t] = y[b * CC + t];
    __syncthreads();

    {   // h[r]: r = t>>4 (0..15), 16-lane group splits the 256-dot
        const int r = t >> 4;
        const int p = t & 15;
        float acc = 0.f;
#pragma unroll
        for (int j = 0; j < 16; ++j)
            acc += ys[p * 16 + j] * W1[r * CC + p * 16 + j];
#pragma unroll
        for (int off = 8; off > 0; off >>= 1) acc += __shfl_xor(acc, off, 16);
        if (p == 0) hs[r] = fmaxf(acc, 0.f);
    }
    __syncthreads();

    float acc = 0.f;
#pragma unroll
    for (int r = 0; r < RR; ++r) acc += hs[r] * W2[t * RR + r];
    const float s = 1.0f / (1.0f + expf(-acc));
    ss[t] = s;
    __syncthreads();

    int cnt = 0;
    for (int j = 0; j < CC; ++j) cnt += (ss[j] < s) ? 1 : 0;
    mask[b * CC + t] = (cnt <= POS - 1) ? 1.0f : 0.0f;
}

// ---------------------------------------------------------------------------
// Kernel 3: zero the masked-off rows of out (~51 of 256 channels per batch).
// One block per row; kept rows exit immediately. Pure writes, no x read.
// ---------------------------------------------------------------------------
__global__ void zero_masked_kernel(const float* __restrict__ mask,
                                   float* __restrict__ out) {
    const int row = blockIdx.x;                      // 0 .. B*C-1
    if (mask[row] != 0.0f) return;                   // kept row: copy stands
    const int t = threadIdx.x;                       // 0 .. 255
    f32x4* orow = (f32x4*)(out + (size_t)row * HWSZ);
    f32x4 z = {0.f, 0.f, 0.f, 0.f};
#pragma unroll
    for (int i = 0; i < 4; ++i)
        __builtin_nontemporal_store(z, &orow[t + i * 256]);
}

extern "C" void kernel_launch(void* const* d_in, const int* in_sizes, int n_in,
                              void* d_out, int out_size, void* d_ws, size_t ws_size,
                              hipStream_t stream) {
    const float* x  = (const float*)d_in[0];
    const float* W1 = (const float*)d_in[1];
    const float* W2 = (const float*)d_in[2];
    float* out = (float*)d_out;

    float* y    = (float*)d_ws;                 // B*C floats
    float* mask = y + BB * CC;                  // B*C floats

    mean_copy_kernel<<<BB * CC, 256, 0, stream>>>(x, out, y);
    se_kernel<<<BB, 256, 0, stream>>>(y, W1, W2, mask);
    zero_masked_kernel<<<BB * CC, 256, 0, stream>>>(mask, out);
}

// Round 6
// 55.071 us; speedup vs baseline: 1.3390x; 1.0578x over previous
//
#include <hip/hip_runtime.h>
#include <math.h>

#define BB 32
#define CC 256
#define HH 64
#define WW 64
#define RR 16
#define HWSZ (HH * WW)          // 4096
#define POS 205                 // max(1, round(0.8 * 256))

typedef float f32x4 __attribute__((ext_vector_type(4)));

// ---------------------------------------------------------------------------
// Kernel 1: fused copy + mean, 2 rows per block (more MLP per thread).
// Plain caching loads (NT loads measured slower than the 6.29 TB/s copy
// pattern); NT stores so the write stream doesn't pollute L2/LLC.
// ---------------------------------------------------------------------------
__global__ void mean_copy_kernel(const float* __restrict__ x,
                                 float* __restrict__ out,
                                 float* __restrict__ y) {
    const int r0 = blockIdx.x * 2;                   // rows r0, r0+1
    const int t = threadIdx.x;                       // 0 .. 255
    const f32x4* x0 = (const f32x4*)(x + (size_t)r0 * HWSZ);
    f32x4* o0 = (f32x4*)(out + (size_t)r0 * HWSZ);

    f32x4 v0[4], v1[4];
#pragma unroll
    for (int i = 0; i < 4; ++i) v0[i] = x0[t + i * 256];
#pragma unroll
    for (int i = 0; i < 4; ++i) v1[i] = x0[1024 + t + i * 256];

    float s0 = 0.f, s1 = 0.f;
#pragma unroll
    for (int i = 0; i < 4; ++i) {
        __builtin_nontemporal_store(v0[i], &o0[t + i * 256]);
        s0 += v0[i].x + v0[i].y + v0[i].z + v0[i].w;
    }
#pragma unroll
    for (int i = 0; i < 4; ++i) {
        __builtin_nontemporal_store(v1[i], &o0[1024 + t + i * 256]);
        s1 += v1[i].x + v1[i].y + v1[i].z + v1[i].w;
    }

#pragma unroll
    for (int off = 32; off > 0; off >>= 1) {
        s0 += __shfl_down(s0, off, 64);
        s1 += __shfl_down(s1, off, 64);
    }
    __shared__ float red[8];
    const int wave = t >> 6;
    if ((t & 63) == 0) { red[wave] = s0; red[wave + 4] = s1; }
    __syncthreads();
    if (t == 0) {
        y[r0]     = (red[0] + red[1] + red[2] + red[3]) * (1.0f / (float)HWSZ);
        y[r0 + 1] = (red[4] + red[5] + red[6] + red[7]) * (1.0f / (float)HWSZ);
    }
}

// ---------------------------------------------------------------------------
// Kernel 2: SE bottleneck + rank-based threshold mask. One block per batch b.
// ---------------------------------------------------------------------------
__global__ void se_kernel(const float* __restrict__ y,
                          const float* __restrict__ W1,
                          const float* __restrict__ W2,
                          float* __restrict__ mask) {
    const int b = blockIdx.x;
    const int t = threadIdx.x;                       // 0 .. 255
    __shared__ float ys[CC];
    __shared__ float hs[RR];
    __shared__ float ss[CC];

    ys[t] = y[b * CC + t];
    __syncthreads();

    {   // h[r]: r = t>>4 (0..15), 16-lane group splits the 256-dot
        const int r = t >> 4;
        const int p = t & 15;
        float acc = 0.f;
#pragma unroll
        for (int j = 0; j < 16; ++j)
            acc += ys[p * 16 + j] * W1[r * CC + p * 16 + j];
#pragma unroll
        for (int off = 8; off > 0; off >>= 1) acc += __shfl_xor(acc, off, 16);
        if (p == 0) hs[r] = fmaxf(acc, 0.f);
    }
    __syncthreads();

    float acc = 0.f;
#pragma unroll
    for (int r = 0; r < RR; ++r) acc += hs[r] * W2[t * RR + r];
    const float s = 1.0f / (1.0f + expf(-acc));
    ss[t] = s;
    __syncthreads();

    int cnt = 0;
    for (int j = 0; j < CC; ++j) cnt += (ss[j] < s) ? 1 : 0;
    mask[b * CC + t] = (cnt <= POS - 1) ? 1.0f : 0.0f;
}

// ---------------------------------------------------------------------------
// Kernel 3: zero the masked-off rows of out (~51 of 256 channels per batch).
// ---------------------------------------------------------------------------
__global__ void zero_masked_kernel(const float* __restrict__ mask,
                                   float* __restrict__ out) {
    const int row = blockIdx.x;                      // 0 .. B*C-1
    if (mask[row] != 0.0f) return;                   // kept row: copy stands
    const int t = threadIdx.x;                       // 0 .. 255
    f32x4* orow = (f32x4*)(out + (size_t)row * HWSZ);
    f32x4 z = {0.f, 0.f, 0.f, 0.f};
#pragma unroll
    for (int i = 0; i < 4; ++i)
        __builtin_nontemporal_store(z, &orow[t + i * 256]);
}

extern "C" void kernel_launch(void* const* d_in, const int* in_sizes, int n_in,
                              void* d_out, int out_size, void* d_ws, size_t ws_size,
                              hipStream_t stream) {
    const float* x  = (const float*)d_in[0];
    const float* W1 = (const float*)d_in[1];
    const float* W2 = (const float*)d_in[2];
    float* out = (float*)d_out;

    float* y    = (float*)d_ws;                 // B*C floats
    float* mask = y + BB * CC;                  // B*C floats

    mean_copy_kernel<<<BB * CC / 2, 256, 0, stream>>>(x, out, y);
    se_kernel<<<BB, 256, 0, stream>>>(y, W1, W2, mask);
    zero_masked_kernel<<<BB * CC, 256, 0, stream>>>(mask, out);
}